// Round 5
// baseline (46.337 us; speedup 1.0000x reference)
//
#include <hip/hip_runtime.h>
#include <math.h>

#define NCLS 81
#define NFG 80
#define KCOMP 11
#define NPROP 1000
#define MAXC 6144
#define DETS 100
#define RMAX 1024

// workspace layout (float indices)
#define WS_M      0                 // [1000] row max of class logits
#define WS_S      1000              // [1000] softmax denom
#define WS_COMPS  2000              // [1000] comp score
#define WS_COMPI  3000              // [1000] comp idx (as float)
#define WS_CAND   4096              // [MAXC][8]: key_lo, key_hi, x1,y1,x2,y2, comp_s, comp_i
#define WS_CNT    (4096 + MAXC*8)   // int: candidate counter
#define WS_DONE   (WS_CNT + 1)      // int: nms completion counter

// 125 blocks x 512 threads; wave w of block b handles row b*8+w.
__global__ __launch_bounds__(512) void prep_kernel(
    const float* __restrict__ cls_logits,
    const float* __restrict__ comp_logits,
    float* __restrict__ ws,
    float* __restrict__ out, int out_size)
{
    int tid = threadIdx.x;
    int bid = blockIdx.x;
    int lane = tid & 63;
    int w = tid >> 6;

    if (bid == 0 && tid == 0) {
        ((int*)ws)[WS_CNT] = 0;
        ((int*)ws)[WS_DONE] = 0;   // zeroed BEFORE nms kernel runs (stream order)
    }
    // output defaults (padded slots): score slots -1, everything else 0
    int oi = bid * 512 + tid;
    if (oi < out_size) out[oi] = (oi >= 400 && oi < 500) ? -1.0f : 0.0f;

    int n = bid * 8 + w;
    if (n >= NPROP) return;

    // ---- class softmax stats (81 values; lanes hold c=lane and c=lane+64) ----
    float x0 = cls_logits[n * NCLS + lane];
    float x1 = (lane < NCLS - 64) ? cls_logits[n * NCLS + 64 + lane] : -INFINITY;
    float m = fmaxf(x0, x1);
    for (int off = 32; off; off >>= 1) m = fmaxf(m, __shfl_xor(m, off));
    float s = expf(x0 - m) + ((lane < NCLS - 64) ? expf(x1 - m) : 0.0f);
    for (int off = 32; off; off >>= 1) s += __shfl_xor(s, off);
    if (lane == 0) { ws[WS_M + n] = m; ws[WS_S + n] = s; }

    // ---- component softmax + fg max/argmax (first occurrence) ----
    float y = (lane < KCOMP) ? comp_logits[n * KCOMP + lane] : -INFINITY;
    float mc = y;
    for (int off = 32; off; off >>= 1) mc = fmaxf(mc, __shfl_xor(mc, off));
    float ec = (lane < KCOMP) ? expf(y - mc) : 0.0f;
    float sc = ec;
    for (int off = 32; off; off >>= 1) sc += __shfl_xor(sc, off);
    float p = (lane >= 1 && lane < KCOMP) ? ec / sc : -1.0f;
    int ci = lane;
    for (int off = 32; off; off >>= 1) {
        float po = __shfl_xor(p, off);
        int   io = __shfl_xor(ci, off);
        if (po > p || (po == p && io < ci)) { p = po; ci = io; }
    }
    if (lane == 0) {
        ws[WS_COMPS + n] = p;
        ws[WS_COMPI + n] = (float)ci;
    }
}

// 80 blocks x 64 threads: per-class NMS; the LAST block to finish then runs
// the histogram-select top-100 (decoupled completion: release fence +
// agent-scope counter + acquire fence orders candidate stores cross-XCD).
__global__ __launch_bounds__(64) void nms_topk_kernel(
    const float* __restrict__ cls_logits,
    const float* __restrict__ boxreg,
    const float* __restrict__ props,
    float* __restrict__ ws,
    float* __restrict__ out)
{
    __shared__ float ls[1024];
    __shared__ int   ln[1024];
    __shared__ float ss[1024];
    __shared__ int   sn[1024];
    __shared__ float sb[1024][4];
    // topk-phase LDS (only the last block touches these)
    __shared__ unsigned long long kk[MAXC];    // 48 KB
    __shared__ int hist[1024];
    __shared__ unsigned long long rkey[RMAX];
    __shared__ int ridx[RMAX];
    __shared__ int rcnt;

    int cfg  = blockIdx.x;   // class c = cfg + 1
    int c    = cfg + 1;
    int lane = threadIdx.x;

    // ---- compute probs for all 16 rounds first (16 loads in flight) ----
    float pv[16];
#pragma unroll
    for (int t = 0; t < 16; ++t) {
        int n = t * 64 + lane;
        if (n < NPROP) {
            float x = cls_logits[n * NCLS + c];
            pv[t] = expf(x - ws[WS_M + n]) / ws[WS_S + n];
        } else {
            pv[t] = 0.0f;
        }
    }

    // ---- compact valid entries (preserves original n-order) ----
    int cnt = 0;
#pragma unroll
    for (int t = 0; t < 16; ++t) {
        int n = t * 64 + lane;
        bool v = (n < NPROP) && (pv[t] > 0.05f);
        unsigned long long bm = __ballot(v);
        if (v) {
            int pos = cnt + __popcll(bm & ((1ull << lane) - 1ull));
            ls[pos] = pv[t]; ln[pos] = n;
        }
        cnt += __popcll(bm);
    }
    int M = cnt;
    __syncthreads();

    // ---- rank sort (descending score, ties by original n order) ----
    for (int i = lane; i < M; i += 64) {
        float si = ls[i];
        int r = 0;
        for (int j = 0; j < M; ++j) {
            float sj = ls[j];
            r += (int)((sj > si) | ((sj == si) & (j < i)));
        }
        ss[r] = si; sn[r] = ln[i];
    }
    __syncthreads();

    // ---- decode + clip boxes for the M sorted candidates only ----
    const float CLIPV = 4.135166556742356f; // log(1000/16)
    for (int p = lane; p < M; p += 64) {
        int n = sn[p];
        float4 r4 = ((const float4*)boxreg)[n * NCLS + c];
        float4 pr = ((const float4*)props)[n];
        float w  = pr.z - pr.x + 1.0f, h = pr.w - pr.y + 1.0f;
        float cx = pr.x + 0.5f * w,  cy = pr.y + 0.5f * h;
        float dx = r4.x / 10.0f, dy = r4.y / 10.0f;
        float dw = fminf(r4.z / 5.0f, CLIPV), dh = fminf(r4.w / 5.0f, CLIPV);
        float pcx = dx * w + cx, pcy = dy * h + cy;
        float pw = expf(dw) * w, ph = expf(dh) * h;
        sb[p][0] = fminf(fmaxf(pcx - 0.5f * pw, 0.0f), 1332.0f);
        sb[p][1] = fminf(fmaxf(pcy - 0.5f * ph, 0.0f), 799.0f);
        sb[p][2] = fminf(fmaxf(pcx + 0.5f * pw - 1.0f, 0.0f), 1332.0f);
        sb[p][3] = fminf(fmaxf(pcy + 0.5f * ph - 1.0f, 0.0f), 799.0f);
    }
    __syncthreads();

    // ---- greedy NMS: keep bits distributed, slot p -> lane p%64, bit p/64 ----
    unsigned int keep = 0;
    for (int k = 0; k < 16; ++k) {
        int p = lane + (k << 6);
        if (p < M) keep |= (1u << k);
    }
    for (int i = 0; i < M; ++i) {
        unsigned int ki = __shfl(keep, i & 63);
        if (!((ki >> (i >> 6)) & 1u)) continue;
        float ax1 = sb[i][0], ay1 = sb[i][1], ax2 = sb[i][2], ay2 = sb[i][3];
        float aarea = (ax2 - ax1 + 1.0f) * (ay2 - ay1 + 1.0f);
        unsigned int km = keep;
        while (km) {
            int k = __ffs(km) - 1; km &= km - 1;
            int p = lane + (k << 6);
            if (p <= i) continue;
            float bx1 = sb[p][0], by1 = sb[p][1], bx2 = sb[p][2], by2 = sb[p][3];
            float barea = (bx2 - bx1 + 1.0f) * (by2 - by1 + 1.0f);
            float lx = fmaxf(ax1, bx1), ly = fmaxf(ay1, by1);
            float rx = fminf(ax2, bx2), ry = fminf(ay2, by2);
            float iw = fmaxf(rx - lx + 1.0f, 0.0f), ih = fmaxf(ry - ly + 1.0f, 0.0f);
            float inter = iw * ih;
            float iou = inter / (aarea + barea - inter);
            if (iou > 0.5f) keep &= ~(1u << k);
        }
    }

    // ---- append survivor records to the global candidate list ----
    int* cntp = &((int*)ws)[WS_CNT];
    for (int k = 0; k < 16; ++k) {
        int p = lane + (k << 6);
        bool v = (p < M) && ((keep >> k) & 1u);
        unsigned long long bm = __ballot(v);
        int cm = __popcll(bm);
        int base = 0;
        if (lane == 0 && cm) base = atomicAdd(cntp, cm);
        base = __shfl(base, 0);
        if (v) {
            int idx = base + __popcll(bm & ((1ull << lane) - 1ull));
            if (idx < MAXC) {
                int n = sn[p];
                unsigned int meta = (unsigned int)(((cfg * NPROP + p) << 10) | n);
                unsigned int khi = __float_as_uint(ss[p]);
                unsigned int klo = ~meta;
                float4* cp = (float4*)&ws[WS_CAND + idx * 8];
                cp[0] = make_float4(__uint_as_float(klo), __uint_as_float(khi),
                                    sb[p][0], sb[p][1]);
                cp[1] = make_float4(sb[p][2], sb[p][3],
                                    ws[WS_COMPS + n], ws[WS_COMPI + n]);
            }
        }
    }

    // ---- decoupled completion: last block does top-k ----
    __threadfence();  // release candidate stores (device scope)
    int old = 0;
    if (lane == 0)
        old = __hip_atomic_fetch_add(&((int*)ws)[WS_DONE], 1,
                                     __ATOMIC_ACQ_REL, __HIP_MEMORY_SCOPE_AGENT);
    old = __shfl(old, 0);
    if (old != NFG - 1) return;

    __threadfence();  // acquire other blocks' stores
    int K = __hip_atomic_load(&((int*)ws)[WS_CNT],
                              __ATOMIC_RELAXED, __HIP_MEMORY_SCOPE_AGENT);
    if (K > MAXC) K = MAXC;

    for (int t = lane; t < 1024; t += 64) hist[t] = 0;
    if (lane == 0) rcnt = 0;
    __syncthreads();

    // ---- load keys (8-deep batches) + histogram top-16 score bits ----
    // score in (0.05,1] -> (bits>>16) in [15692,16256]; bucket = (bits>>16)-15360.
    for (int j0 = 0; j0 < K; j0 += 512) {
        unsigned long long a[8];
#pragma unroll
        for (int t = 0; t < 8; ++t) {
            int j = j0 + t * 64 + lane;
            a[t] = (j < K) ? *(const unsigned long long*)&ws[WS_CAND + j * 8] : 0ull;
        }
#pragma unroll
        for (int t = 0; t < 8; ++t) {
            int j = j0 + t * 64 + lane;
            if (j < K) {
                kk[j] = a[t];
                int b = (int)((unsigned int)(a[t] >> 48)) - 15360;
                b = b < 0 ? 0 : (b > 1023 ? 1023 : b);
                atomicAdd(&hist[b], 1);
            }
        }
    }
    __syncthreads();

    // ---- in-place suffix count S[b] = #keys in buckets > b (one wave) ----
    {
        int base = lane * 16;
        int tot = 0;
#pragma unroll
        for (int t = 0; t < 16; ++t) tot += hist[base + t];
        int sfx = tot;
        for (int off = 1; off < 64; off <<= 1) {
            int o = __shfl_down(sfx, off);
            if (lane + off < 64) sfx += o;
        }
        int run = sfx - tot;  // count in higher lanes' buckets
        for (int t = 15; t >= 0; --t) {
            int h = hist[base + t];
            hist[base + t] = run;
            run += h;
        }
    }
    __syncthreads();

    // ---- compact R = keys whose higher-bucket count < DETS ----
    for (int j = lane; j < K; j += 64) {
        unsigned long long k = kk[j];
        int b = (int)((unsigned int)(k >> 48)) - 15360;
        b = b < 0 ? 0 : (b > 1023 ? 1023 : b);
        if (hist[b] < DETS) {
            int pos = atomicAdd(&rcnt, 1);
            if (pos < RMAX) { rkey[pos] = k; ridx[pos] = j; }
        }
    }
    __syncthreads();
    int R = rcnt < RMAX ? rcnt : RMAX;

    // ---- exact rank within R (== global rank, by bucket monotonicity) ----
    for (int i = lane; i < R; i += 64) {
        unsigned long long ki = rkey[i];
        int r = 0;
        int j = 0;
        for (; j + 16 <= R; j += 16) {
            unsigned long long a[16];
#pragma unroll
            for (int t = 0; t < 16; ++t) a[t] = rkey[j + t];
#pragma unroll
            for (int t = 0; t < 16; ++t) r += (int)(a[t] > ki);
        }
        for (; j < R; ++j) r += (int)(rkey[j] > ki);

        if (r < DETS) {
            const float4* cp = (const float4*)&ws[WS_CAND + ridx[i] * 8];
            float4 a = cp[0], b = cp[1];
            unsigned int meta = ~__float_as_uint(a.x);
            float score = a.y;  // key_hi bits == score bits
            out[r * 4 + 0] = a.z;
            out[r * 4 + 1] = a.w;
            out[r * 4 + 2] = b.x;
            out[r * 4 + 3] = b.y;
            out[400 + r] = score;
            out[500 + r] = b.z;
            out[600 + r] = (float)((meta >> 10) / NPROP + 1);
            out[700 + r] = b.w;
        }
    }
}

extern "C" void kernel_launch(void* const* d_in, const int* in_sizes, int n_in,
                              void* d_out, int out_size, void* d_ws, size_t ws_size,
                              hipStream_t stream)
{
    const float* cls  = (const float*)d_in[0];
    const float* comp = (const float*)d_in[1];
    const float* breg = (const float*)d_in[2];
    const float* prop = (const float*)d_in[3];
    float* ws  = (float*)d_ws;
    float* out = (float*)d_out;

    hipLaunchKernelGGL(prep_kernel, dim3(125), dim3(512), 0, stream,
                       cls, comp, ws, out, out_size);
    hipLaunchKernelGGL(nms_topk_kernel, dim3(NFG), dim3(64), 0, stream,
                       cls, breg, prop, ws, out);
}